// Round 1
// baseline (132.058 us; speedup 1.0000x reference)
//
#include <hip/hip_runtime.h>

// Problem: VQ-VAE codebook forward, B=8,C=64,H=64,W=64, K=8192, D=64.
// Reference quirk: distance uses a SCALAR cross term, so argmin over k is
// independent of n: idx[n] == argmin_k |book_k|^2 for all n.
// Outputs (concatenated float32):
//   [0 .. 2097151]  z_q permuted to [B,W,C,H]: out[b,w,c,h] = e[w], e=book[kmin]
//   [2097152 .. 2129919] idx: 32768 x float(kmin)
//   [2129920]       loss = 1.25 * mean((e[w] - in[b,c,h,w])^2)

#define NTOT   2097152   // 8*64*64*64
#define NIDX   32768
#define K_ROWS 8192

// ws layout: [0..7] u64 packed argmin key, [8..11] float loss acc, [12..15] u32 done ctr

__global__ void argmin_norm_kernel(const float* __restrict__ book,
                                   unsigned long long* __restrict__ ws_key) {
    // 512 blocks x 256 threads; each block handles 16 rows, 16 lanes per row.
    const int t    = threadIdx.x;
    const int rIn  = t >> 4;          // row within block, 0..15
    const int c4   = t & 15;          // float4 column, 0..15
    const int row  = blockIdx.x * 16 + rIn;

    float4 v = ((const float4*)book)[row * 16 + c4];
    float s = v.x * v.x + v.y * v.y + v.z * v.z + v.w * v.w;
    // reduce across the 16 lanes of this row (lanes are contiguous in the wave)
    s += __shfl_down(s, 8, 16);
    s += __shfl_down(s, 4, 16);
    s += __shfl_down(s, 2, 16);
    s += __shfl_down(s, 1, 16);

    __shared__ unsigned long long keys[16];
    if (c4 == 0) {
        // positive float bits are monotone as uint -> pack (norm, row); min key
        // gives min norm with ties broken to the LOWEST row (jnp.argmin semantics).
        unsigned int bits = __float_as_uint(s);
        keys[rIn] = ((unsigned long long)bits << 32) | (unsigned int)row;
    }
    __syncthreads();
    if (t == 0) {
        unsigned long long k = keys[0];
        #pragma unroll
        for (int i = 1; i < 16; ++i) k = k < keys[i] ? k : keys[i];
        atomicMin(ws_key, k);
    }
}

__global__ __launch_bounds__(256) void vq_main_kernel(
        const float* __restrict__ in, const float* __restrict__ book,
        float* __restrict__ out,
        const unsigned long long* __restrict__ ws_key,
        float* __restrict__ ws_acc, unsigned int* __restrict__ ws_done) {
    const int tid = blockIdx.x * blockDim.x + threadIdx.x;   // 524288 threads

    const unsigned long long key = *ws_key;                  // written by prev kernel
    const int kmin = (int)(key & 0xFFFFFFFFu);
    const float* __restrict__ e = book + kmin * 64;          // 256B-aligned

    // ---- idx output: 32768 floats == float(kmin), as 8192 float4 stores ----
    if (tid < NIDX / 4) {
        const float kf = (float)kmin;
        ((float4*)(out + NTOT))[tid] = make_float4(kf, kf, kf, kf);
    }

    // ---- z_q output [B,W,C,H]: o = b*262144 + w*4096 + c*64 + h -> value e[w] ----
    {
        const int o = tid * 4;                 // 4 consecutive h, same w
        const float ev = e[(o >> 12) & 63];
        ((float4*)out)[tid] = make_float4(ev, ev, ev, ev);
    }

    // ---- loss partial over input [B,C,H,W]: i = tid*4, w = i & 63 ----
    float part;
    {
        const float4 z  = ((const float4*)in)[tid];
        const float4 ef = ((const float4*)e)[tid & 15];      // w/4 column
        const float d0 = z.x - ef.x, d1 = z.y - ef.y;
        const float d2 = z.z - ef.z, d3 = z.w - ef.w;
        part = d0 * d0 + d1 * d1 + d2 * d2 + d3 * d3;
    }
    // wave (64-lane) shuffle reduction
    #pragma unroll
    for (int off = 32; off > 0; off >>= 1) part += __shfl_down(part, off, 64);

    __shared__ float sp[4];
    const int lane = threadIdx.x & 63, wid = threadIdx.x >> 6;
    if (lane == 0) sp[wid] = part;
    __syncthreads();
    if (threadIdx.x == 0) {
        const float bs = sp[0] + sp[1] + sp[2] + sp[3];
        atomicAdd(ws_acc, bs);                 // device-scope by default on CDNA
        __threadfence();
        const unsigned int done = atomicAdd(ws_done, 1u);
        if (done == gridDim.x - 1) {
            // last block: read full sum device-scope and finalize
            const float total = atomicAdd(ws_acc, 0.0f);
            out[NTOT + NIDX] = total * (1.25f / (float)NTOT);
        }
    }
}

extern "C" void kernel_launch(void* const* d_in, const int* in_sizes, int n_in,
                              void* d_out, int out_size, void* d_ws, size_t ws_size,
                              hipStream_t stream) {
    const float* in   = (const float*)d_in[0];   // [8,64,64,64] fp32
    const float* book = (const float*)d_in[1];   // [8192,64] fp32
    float* out = (float*)d_out;

    unsigned long long* ws_key  = (unsigned long long*)d_ws;
    float*              ws_acc  = (float*)((char*)d_ws + 8);
    unsigned int*       ws_done = (unsigned int*)((char*)d_ws + 12);

    // init: key = 0xFF.. (u64 max), acc = 0, done = 0  (memset nodes are capture-safe)
    hipMemsetAsync(d_ws, 0xFF, 8, stream);
    hipMemsetAsync((char*)d_ws + 8, 0, 8, stream);

    argmin_norm_kernel<<<K_ROWS / 16, 256, 0, stream>>>(book, ws_key);
    vq_main_kernel<<<NTOT / 4 / 256, 256, 0, stream>>>(in, book, out, ws_key, ws_acc, ws_done);
}

// Round 2
// 70.562 us; speedup vs baseline: 1.8715x; 1.8715x over previous
//
#include <hip/hip_runtime.h>

// VQ-VAE codebook forward, B=8,C=64,H=64,W=64, K=8192, D=64.
// Reference quirk: the cross term is a SCALAR, so argmin over k is independent
// of n: idx[n] == argmin_k |book_k|^2 for all n.
// Outputs (concatenated float32):
//   [0 .. 2097151]      z_q permuted to [B,W,C,H]: out[b,w,c,h] = e[w], e=book[kmin]
//   [2097152..2129919]  idx: 32768 x float(kmin)
//   [2129920]           loss = 1.25 * mean((e[w] - in[b,c,h,w])^2)
//
// R2 design: NO same-address atomics anywhere (R1 lost ~120 us to contended
// atomicMin/atomicAdd serialization). Per-block partials -> plain stores ->
// tiny graph-sequenced reduction kernels.

#define NTOT    2097152   // 8*64*64*64
#define NIDX    32768
#define K_ROWS  8192
#define K1_BLK  32        // 32 blocks x 256 threads = 8192 rows, 1 row/thread
#define K2_BLK  1024      // main kernel blocks
#define K2_ITER 2         // 524288 float4 tasks / (1024*256)

// ws layout: [0..255] 32 x u64 per-block argmin keys; [256..] 1024 x float loss partials

__global__ __launch_bounds__(256) void k1_argmin(const float* __restrict__ book,
                                                 unsigned long long* __restrict__ ws_keys) {
    const int row = blockIdx.x * 256 + threadIdx.x;   // one codebook row per thread
    const float4* r = (const float4*)(book + row * 64);
    float s = 0.f;
    #pragma unroll
    for (int j = 0; j < 16; ++j) {
        float4 v = r[j];
        s += v.x * v.x + v.y * v.y + v.z * v.z + v.w * v.w;
    }
    // pack (norm_bits, row): positive-float bits are monotone as uint;
    // u64 min => min norm, ties to lowest row (jnp.argmin semantics).
    unsigned long long key = ((unsigned long long)__float_as_uint(s) << 32)
                           | (unsigned int)row;
    // wave min (64 lanes)
    #pragma unroll
    for (int off = 32; off > 0; off >>= 1) {
        unsigned long long o = __shfl_down(key, off, 64);
        key = o < key ? o : key;
    }
    __shared__ unsigned long long sk[4];
    const int lane = threadIdx.x & 63, wid = threadIdx.x >> 6;
    if (lane == 0) sk[wid] = key;
    __syncthreads();
    if (threadIdx.x == 0) {
        unsigned long long k = sk[0];
        #pragma unroll
        for (int i = 1; i < 4; ++i) k = sk[i] < k ? sk[i] : k;
        ws_keys[blockIdx.x] = k;              // plain store, no atomic
    }
}

__global__ __launch_bounds__(256) void k2_main(const float* __restrict__ in,
                                               const float* __restrict__ book,
                                               float* __restrict__ out,
                                               const unsigned long long* __restrict__ ws_keys,
                                               float* __restrict__ ws_part) {
    // ---- resolve kmin: each wave redundantly min-reduces the 32 keys (L2-hot) ----
    const int lane = threadIdx.x & 63, wid = threadIdx.x >> 6;
    unsigned long long key = (lane < K1_BLK) ? ws_keys[lane] : ~0ULL;
    #pragma unroll
    for (int off = 32; off > 0; off >>= 1) {
        unsigned long long o = __shfl_down(key, off, 64);
        key = o < key ? o : key;
    }
    key = __shfl(key, 0, 64);                 // broadcast within wave
    const int kmin = (int)(key & 0xFFFFFFFFu);
    const float* __restrict__ e = book + kmin * 64;

    const int tid = blockIdx.x * 256 + threadIdx.x;   // 262144 threads

    // ---- idx output: 32768 floats == float(kmin) ----
    if (tid < NIDX / 4) {
        const float kf = (float)kmin;
        ((float4*)(out + NTOT))[tid] = make_float4(kf, kf, kf, kf);
    }

    // ---- z_q out [B,W,C,H] + fused loss over in [B,C,H,W], 2 float4s/thread ----
    float part = 0.f;
    #pragma unroll
    for (int it = 0; it < K2_ITER; ++it) {
        const int i = tid + it * (K2_BLK * 256);      // float4 index
        // z_q: float offset o=4i -> value e[(o>>12)&63]
        const float ev = e[(i >> 10) & 63];
        ((float4*)out)[i] = make_float4(ev, ev, ev, ev);
        // loss: in float4 i covers w = (4i&63)..+3
        const float4 z  = ((const float4*)in)[i];
        const float4 ef = ((const float4*)e)[i & 15];
        const float d0 = z.x - ef.x, d1 = z.y - ef.y;
        const float d2 = z.z - ef.z, d3 = z.w - ef.w;
        part += d0 * d0 + d1 * d1 + d2 * d2 + d3 * d3;
    }
    #pragma unroll
    for (int off = 32; off > 0; off >>= 1) part += __shfl_down(part, off, 64);

    __shared__ float sp[4];
    if (lane == 0) sp[wid] = part;
    __syncthreads();
    if (threadIdx.x == 0)
        ws_part[blockIdx.x] = sp[0] + sp[1] + sp[2] + sp[3];   // plain store
}

__global__ __launch_bounds__(256) void k3_loss(const float* __restrict__ ws_part,
                                               float* __restrict__ out) {
    // single block: sum 1024 partials
    float s = 0.f;
    #pragma unroll
    for (int it = 0; it < 4; ++it) s += ws_part[threadIdx.x + it * 256];
    #pragma unroll
    for (int off = 32; off > 0; off >>= 1) s += __shfl_down(s, off, 64);
    __shared__ float sp[4];
    const int lane = threadIdx.x & 63, wid = threadIdx.x >> 6;
    if (lane == 0) sp[wid] = s;
    __syncthreads();
    if (threadIdx.x == 0)
        out[NTOT + NIDX] = (sp[0] + sp[1] + sp[2] + sp[3]) * (1.25f / (float)NTOT);
}

extern "C" void kernel_launch(void* const* d_in, const int* in_sizes, int n_in,
                              void* d_out, int out_size, void* d_ws, size_t ws_size,
                              hipStream_t stream) {
    const float* in   = (const float*)d_in[0];   // [8,64,64,64] fp32
    const float* book = (const float*)d_in[1];   // [8192,64] fp32
    float* out = (float*)d_out;

    unsigned long long* ws_keys = (unsigned long long*)d_ws;
    float*              ws_part = (float*)((char*)d_ws + 256);

    k1_argmin<<<K1_BLK, 256, 0, stream>>>(book, ws_keys);
    k2_main<<<K2_BLK, 256, 0, stream>>>(in, book, out, ws_keys, ws_part);
    k3_loss<<<1, 256, 0, stream>>>(ws_part, out);
}

// Round 3
// 67.526 us; speedup vs baseline: 1.9557x; 1.0450x over previous
//
#include <hip/hip_runtime.h>

// VQ-VAE codebook forward, B=8,C=64,H=64,W=64, K=8192, D=64.
// Reference quirk: the cross term is a SCALAR, so argmin over k is independent
// of n: idx[n] == argmin_k |book_k|^2 for all n.
// Outputs (concatenated float32):
//   [0 .. 2097151]      z_q permuted to [B,W,C,H]: out[b,w,c,h] = e[w], e=book[kmin]
//   [2097152..2129919]  idx: 32768 x float(kmin)
//   [2129920]           loss = 1.25 * mean((e[w] - in[b,c,h,w])^2)
//
// R3: k1 parallelism fix (32 -> 512 blocks; R2's k1 was latency-bound with only
// 128 waves chip-wide). No same-address atomics anywhere (R1 lesson).
// Note: ~45-50 us of dur_us is the harness's 256 MB d_ws re-poison (fill
// kernels at 42 us in the profile) -- outside our control.

#define NTOT    2097152   // 8*64*64*64
#define NIDX    32768
#define K_ROWS  8192
#define K1_BLK  512       // 16 rows/block, 16 lanes (one float4) per row
#define K2_BLK  512
#define K2_ITER 4         // 524288 float4 tasks / (512*256)

// ws layout: [0 .. 4095] 512 x u64 per-block argmin keys
//            [4096 .. ]  512 x float loss partials

__global__ __launch_bounds__(256) void k1_argmin(const float* __restrict__ book,
                                                 unsigned long long* __restrict__ ws_keys) {
    const int t   = threadIdx.x;
    const int rIn = t >> 4;                       // row within block, 0..15
    const int c4  = t & 15;                       // float4 column
    const int row = blockIdx.x * 16 + rIn;

    const float4 v = ((const float4*)book)[row * 16 + c4];   // fully coalesced
    float s = v.x * v.x + v.y * v.y + v.z * v.z + v.w * v.w;
    // reduce across the 16 contiguous lanes of this row
    s += __shfl_down(s, 8, 16);
    s += __shfl_down(s, 4, 16);
    s += __shfl_down(s, 2, 16);
    s += __shfl_down(s, 1, 16);

    __shared__ unsigned long long keys[16];
    if (c4 == 0) {
        // positive-float bits are monotone as uint -> u64 min gives min norm,
        // ties broken to LOWEST row (jnp.argmin semantics).
        keys[rIn] = ((unsigned long long)__float_as_uint(s) << 32)
                  | (unsigned int)row;
    }
    __syncthreads();
    if (t == 0) {
        unsigned long long k = keys[0];
        #pragma unroll
        for (int i = 1; i < 16; ++i) k = keys[i] < k ? keys[i] : k;
        ws_keys[blockIdx.x] = k;                  // plain store, no atomic
    }
}

__global__ __launch_bounds__(256) void k2_main(const float* __restrict__ in,
                                               const float* __restrict__ book,
                                               float* __restrict__ out,
                                               const unsigned long long* __restrict__ ws_keys,
                                               float* __restrict__ ws_part) {
    const int lane = threadIdx.x & 63, wid = threadIdx.x >> 6;

    // ---- resolve kmin: wave 0 reduces the 512 L2-hot keys, LDS-broadcast ----
    __shared__ unsigned long long skey;
    if (wid == 0) {
        unsigned long long key = ~0ULL;
        #pragma unroll
        for (int j = 0; j < K1_BLK / 64; ++j) {   // 8 strided loads per lane
            unsigned long long o = ws_keys[lane + j * 64];
            key = o < key ? o : key;
        }
        #pragma unroll
        for (int off = 32; off > 0; off >>= 1) {
            unsigned long long o = __shfl_down(key, off, 64);
            key = o < key ? o : key;
        }
        if (lane == 0) skey = key;
    }
    __syncthreads();
    const int kmin = (int)(skey & 0xFFFFFFFFu);
    const float* __restrict__ e = book + kmin * 64;   // L2-hot broadcast

    const int tid = blockIdx.x * 256 + threadIdx.x;   // 131072 threads

    // ---- idx output: 32768 floats == float(kmin) (blocks 0..31) ----
    if (tid < NIDX / 4) {
        const float kf = (float)kmin;
        ((float4*)(out + NTOT))[tid] = make_float4(kf, kf, kf, kf);
    }

    // ---- z_q out [B,W,C,H] + fused loss over in [B,C,H,W], 4 float4/thread ----
    float part = 0.f;
    #pragma unroll
    for (int it = 0; it < K2_ITER; ++it) {
        const int i = tid + it * (K2_BLK * 256);       // float4 index
        // z_q: float offset o=4i -> value e[(o>>12)&63]
        const float ev = e[(i >> 10) & 63];
        ((float4*)out)[i] = make_float4(ev, ev, ev, ev);
        // loss: in float4 i covers w = (4i&63)..+3
        const float4 z  = ((const float4*)in)[i];
        const float4 ef = ((const float4*)e)[i & 15];
        const float d0 = z.x - ef.x, d1 = z.y - ef.y;
        const float d2 = z.z - ef.z, d3 = z.w - ef.w;
        part += d0 * d0 + d1 * d1 + d2 * d2 + d3 * d3;
    }
    #pragma unroll
    for (int off = 32; off > 0; off >>= 1) part += __shfl_down(part, off, 64);

    __shared__ float sp[4];
    if (lane == 0) sp[wid] = part;
    __syncthreads();
    if (threadIdx.x == 0)
        ws_part[blockIdx.x] = sp[0] + sp[1] + sp[2] + sp[3];   // plain store
}

__global__ __launch_bounds__(64) void k3_loss(const float* __restrict__ ws_part,
                                              float* __restrict__ out) {
    // single wave: sum 512 partials
    float s = 0.f;
    #pragma unroll
    for (int j = 0; j < K2_BLK / 64; ++j) s += ws_part[threadIdx.x + j * 64];
    #pragma unroll
    for (int off = 32; off > 0; off >>= 1) s += __shfl_down(s, off, 64);
    if (threadIdx.x == 0)
        out[NTOT + NIDX] = s * (1.25f / (float)NTOT);
}

extern "C" void kernel_launch(void* const* d_in, const int* in_sizes, int n_in,
                              void* d_out, int out_size, void* d_ws, size_t ws_size,
                              hipStream_t stream) {
    const float* in   = (const float*)d_in[0];   // [8,64,64,64] fp32
    const float* book = (const float*)d_in[1];   // [8192,64] fp32
    float* out = (float*)d_out;

    unsigned long long* ws_keys = (unsigned long long*)d_ws;
    float*              ws_part = (float*)((char*)d_ws + 4096);

    k1_argmin<<<K1_BLK, 256, 0, stream>>>(book, ws_keys);
    k2_main<<<K2_BLK, 256, 0, stream>>>(in, book, out, ws_keys, ws_part);
    k3_loss<<<1, 64, 0, stream>>>(ws_part, out);
}